// Round 12
// baseline (226.558 us; speedup 1.0000x reference)
//
#include <hip/hip_runtime.h>

// NeuralODEFlow, slice-local formulation (13 launches):
//   trace_t = (S_{t+1}-S_t)*dt/H + g_{t+1}*dt,  S=sum_j mlp(z)_j, g=m1^T E m2
//   E[u,v] = W2[u,v]*(W3@W1)[v,u].  MFMA 16x16x32 bf16; y-path hi/lo 3-product
//   split (Al*Bl dropped, ~2^-18); T-path single bf16.
// Round-9: 512 blocks (2/CU, 4 waves/SIMD), fragment-linear LDS (conflict-free
// ds_read_b128), split accumulator chains, K-halved phase 2.

#define HD 512
#define DD 64
#define NB 1024

typedef __attribute__((ext_vector_type(8))) short short8;   // 8 bf16
typedef __attribute__((ext_vector_type(4))) float f32x4;

__device__ __forceinline__ unsigned short bf16_rn(float x) {
  unsigned int u = __float_as_uint(x);
  u += 0x7FFFu + ((u >> 16) & 1u);
  return (unsigned short)(u >> 16);
}
__device__ __forceinline__ float bf16_f(unsigned short h) {
  return __uint_as_float(((unsigned int)h) << 16);
}
#define MFMA(a, b, c) __builtin_amdgcn_mfma_f32_16x16x32_bf16(a, b, c, 0, 0, 0)

// ---------------- k_prep: pack W1/W2 (hi/lo), E, W3 (hi/lo); zero logdet ----
// grid 64 (kc 16 x kg 4), block 512 (nc 32 x nl 16). All stores contiguous 16 B.
__global__ __launch_bounds__(512) void k_prep(const float* __restrict__ W1,
    const float* __restrict__ W2, const float* __restrict__ W3,
    short* __restrict__ W1h, short* __restrict__ W1l,
    short* __restrict__ W2h, short* __restrict__ W2l, short* __restrict__ Ep,
    short* __restrict__ W3h, short* __restrict__ W3l,
    float* __restrict__ logdet) {
  int bid = blockIdx.x;
  int kc = bid >> 2, kg = bid & 3;
  int tid = threadIdx.x;
  int nc = tid >> 4, nl = tid & 15;
  int u0 = kc * 32 + kg * 8;
  int n = nc * 16 + nl;
  if (bid < 2) logdet[bid * 512 + tid] = 0.f;
  float s[8];
#pragma unroll
  for (int j = 0; j < 8; ++j) s[j] = 0.f;
  for (int q = 0; q < DD; q += 4) {
    float4 w3q = *(const float4*)(W3 + n * DD + q);
#pragma unroll
    for (int i = 0; i < 4; ++i) {
      float wq = (i == 0) ? w3q.x : (i == 1) ? w3q.y : (i == 2) ? w3q.z : w3q.w;
      float4 a = *(const float4*)(W1 + (q + i) * HD + u0);
      float4 b = *(const float4*)(W1 + (q + i) * HD + u0 + 4);
      s[0] = fmaf(wq, a.x, s[0]); s[1] = fmaf(wq, a.y, s[1]);
      s[2] = fmaf(wq, a.z, s[2]); s[3] = fmaf(wq, a.w, s[3]);
      s[4] = fmaf(wq, b.x, s[4]); s[5] = fmaf(wq, b.y, s[5]);
      s[6] = fmaf(wq, b.z, s[6]); s[7] = fmaf(wq, b.w, s[7]);
    }
  }
  long off = ((long)(kc * 32 + nc) * 64 + kg * 16 + nl) * 8;
  short8 vh, vl, ve;
#pragma unroll
  for (int j = 0; j < 8; ++j) {
    float w2 = W2[(u0 + j) * HD + n];
    unsigned short uh = bf16_rn(w2);
    vh[j] = (short)uh;
    vl[j] = (short)bf16_rn(w2 - bf16_f(uh));
    ve[j] = (short)bf16_rn(w2 * s[j]);
  }
  *(short8*)(W2h + off) = vh;
  *(short8*)(W2l + off) = vl;
  *(short8*)(Ep + off) = ve;
  if (kc < 2) {
    short8 ah, al;
#pragma unroll
    for (int j = 0; j < 8; ++j) {
      float w1 = W1[(u0 + j) * HD + n];
      unsigned short uh = bf16_rn(w1);
      ah[j] = (short)uh;
      al[j] = (short)bf16_rn(w1 - bf16_f(uh));
    }
    *(short8*)(W1h + off) = ah;
    *(short8*)(W1l + off) = al;
  }
  if (nc < 4) {
    long off3 = ((long)(kc * 4 + nc) * 64 + kg * 16 + nl) * 8;
    short8 th, tl;
#pragma unroll
    for (int sub = 0; sub < 8; ++sub) {
      float w3v = W3[(u0 + sub) * DD + n];
      unsigned short uh = bf16_rn(w3v);
      th[sub] = (short)uh;
      tl[sub] = (short)bf16_rn(w3v - bf16_f(uh));
    }
    *(short8*)(W3h + off3) = th;
    *(short8*)(W3l + off3) = tl;
  }
}

// ---------------- k_step ----------------
// grid 512 = 64 rowgroups (16 rows) x 8 col-slices (64 v). 512 threads, 8 waves.
// Fragment-linear LDS: element (k,m-or-n) of a 16x(32*KC) A-operand lives at
// ((kc*64 + lane)*8 + j) shorts, lane = ((k>>3)&3)*16 + m, j = k&7.
__global__ __launch_bounds__(512, 4) void k_step(
    const float* __restrict__ zin, float* __restrict__ zout,
    const float* __restrict__ yPartR, const float* __restrict__ gR,
    const float* __restrict__ SRead, float* __restrict__ SWrite,
    float* __restrict__ logdet,
    const float* __restrict__ b1, const float* __restrict__ b2,
    const float* __restrict__ b3,
    const short* __restrict__ W1h, const short* __restrict__ W1l,
    const short* __restrict__ W2h, const short* __restrict__ W2l,
    const short* __restrict__ Ep,
    const short* __restrict__ W3h, const short* __restrict__ W3l,
    float* __restrict__ yPartW, float* __restrict__ gW,
    float dt, float dtp, float dtHp, int mode) {
  __shared__ __align__(16) short zh[2 * 64 * 8];    // 2 KB, frag-linear
  __shared__ __align__(16) short zl[2 * 64 * 8];
  __shared__ __align__(16) short hh[16 * 64 * 8];   // 16 KB each
  __shared__ __align__(16) short hl[16 * 64 * 8];
  __shared__ __align__(16) short hm[16 * 64 * 8];
  __shared__ __align__(16) short h2h[2 * 64 * 8];   // 2 KB each
  __shared__ __align__(16) short h2l[2 * 64 * 8];
  __shared__ __align__(16) float scrH[4 * 64 * 4];  // 4 KB each
  __shared__ __align__(16) float scrT[4 * 64 * 4];
  __shared__ float gred[64];
  int bid = blockIdx.x;
  int cs = bid & 7;            // 64-col slice
  int r0 = (bid >> 3) << 4;    // 16-row group
  int tid = threadIdx.x;
  int l = tid & 63;
  int w = tid >> 6;
  int mrow = l & 15;
  int kg = l >> 4;

  // ---- phase 0: y_{k-1} sum, Euler, S, deferred logdet; z -> frag-linear LDS ----
#pragma unroll
  for (int half = 0; half < 2; ++half) {
    int rr = w + half * 8;
    int row = r0 + rr;
    float zv = zin[row * DD + l];
    float yv = 0.f;
    if (mode) {
#pragma unroll
      for (int s = 0; s < 8; ++s) yv += yPartR[(s * NB + row) * DD + l];
      yv += b3[l];
      zv = fmaf(yv, dt, zv);
    }
    if (cs == 0) zout[row * DD + l] = zv;
    unsigned short hx = bf16_rn(zv);
    int offs = (((l >> 5) * 64 + ((l >> 3) & 3) * 16 + rr) << 3) + (l & 7);
    zh[offs] = (short)hx;
    zl[offs] = (short)bf16_rn(zv - bf16_f(hx));
    if (mode) {
      float sv = yv;
#pragma unroll
      for (int m = 1; m < 64; m <<= 1) sv += __shfl_xor(sv, m);
      if (l == 0 && cs == 0) {
        SWrite[row] = sv;
        if (mode == 2) {
          float g = 0.f;
#pragma unroll
          for (int s = 0; s < 8; ++s) g += gR[s * NB + row];
          logdet[row] -= (sv - SRead[row]) * dtHp + g * dtp;
        }
      }
    }
  }
  __syncthreads();

  // ---- phase 1: h1 = relu(z@W1+b1), all 512 cols, frag-linear out ----
  {
    short8 az0h = *(const short8*)(zh + l * 8);
    short8 az0l = *(const short8*)(zl + l * 8);
    short8 az1h = *(const short8*)(zh + (64 + l) * 8);
    short8 az1l = *(const short8*)(zl + (64 + l) * 8);
    for (int i = 0; i < 4; ++i) {
      int nc = w * 4 + i;
      short8 b0h = *(const short8*)(W1h + ((long)(nc) * 64 + l) * 8);
      short8 b0l = *(const short8*)(W1l + ((long)(nc) * 64 + l) * 8);
      short8 c1h = *(const short8*)(W1h + ((long)(32 + nc) * 64 + l) * 8);
      short8 c1l = *(const short8*)(W1l + ((long)(32 + nc) * 64 + l) * 8);
      f32x4 aA = {0.f, 0.f, 0.f, 0.f};
      f32x4 aB = {0.f, 0.f, 0.f, 0.f};
      aA = MFMA(az0h, b0h, aA); aB = MFMA(az0h, b0l, aB);
      aA = MFMA(az0l, b0h, aA); aB = MFMA(az1h, c1l, aB);
      aA = MFMA(az1h, c1h, aA); aB = MFMA(az1l, c1h, aB);
      int n = nc * 16 + mrow;
      float bb = b1[n];
      int kcA = nc >> 1;
      int kgA = (nc * 2 + (mrow >> 3)) & 3;
#pragma unroll
      for (int reg = 0; reg < 4; ++reg) {
        float h = fmaxf(aA[reg] + aB[reg] + bb, 0.f);
        int r = kg * 4 + reg;
        unsigned short uh = bf16_rn(h);
        unsigned short ul = bf16_rn(h - bf16_f(uh));
        unsigned short um = (h > 0.f) ? 0x3F80u : 0u;
        int ph = __shfl_xor((int)uh, 1);
        int pl = __shfl_xor((int)ul, 1);
        int pm = __shfl_xor((int)um, 1);
        if ((l & 1) == 0) {
          int base = ((kcA * 64 + kgA * 16 + r) << 3) + (mrow & 7);
          *(unsigned int*)(hh + base) = (unsigned int)uh | (((unsigned int)(unsigned short)ph) << 16);
          *(unsigned int*)(hl + base) = (unsigned int)ul | (((unsigned int)(unsigned short)pl) << 16);
          *(unsigned int*)(hm + base) = (unsigned int)um | (((unsigned int)(unsigned short)pm) << 16);
        }
      }
    }
  }
  __syncthreads();

  // ---- phase 2: h2 = relu(h1@W2+b2), T = m1@E; K halved across wave pairs ----
  {
    int nch = w & 3;
    int kh = w >> 2;
    int ncg = cs * 4 + nch;
    f32x4 aP = {0.f, 0.f, 0.f, 0.f};
    f32x4 aQ = {0.f, 0.f, 0.f, 0.f};
    f32x4 aT = {0.f, 0.f, 0.f, 0.f};
#pragma unroll 2
    for (int kk = 0; kk < 8; ++kk) {
      int kc = kh * 8 + kk;
      short8 Ah = *(const short8*)(hh + (kc * 64 + l) * 8);
      short8 Al = *(const short8*)(hl + (kc * 64 + l) * 8);
      short8 Am = *(const short8*)(hm + (kc * 64 + l) * 8);
      long boff = ((long)(kc * 32 + ncg) * 64 + l) * 8;
      short8 Bh = *(const short8*)(W2h + boff);
      short8 Bl = *(const short8*)(W2l + boff);
      short8 Be = *(const short8*)(Ep + boff);
      aP = MFMA(Ah, Bh, aP);
      aQ = MFMA(Ah, Bl, aQ);
      aP = MFMA(Al, Bh, aP);
      aT = MFMA(Am, Be, aT);
    }
    f32x4 aH;
#pragma unroll
    for (int i = 0; i < 4; ++i) aH[i] = aP[i] + aQ[i];
    if (kh) {
      *(f32x4*)(scrH + (nch * 64 + l) * 4) = aH;
      *(f32x4*)(scrT + (nch * 64 + l) * 4) = aT;
    }
    __syncthreads();
    if (!kh) {
      f32x4 pH = *(const f32x4*)(scrH + (nch * 64 + l) * 4);
      f32x4 pT = *(const f32x4*)(scrT + (nch * 64 + l) * 4);
      int n = ncg * 16 + mrow;
      float bb2 = b2[n];
      float h2v[4], gq[4];
#pragma unroll
      for (int reg = 0; reg < 4; ++reg) {
        float hv = aH[reg] + pH[reg] + bb2;
        h2v[reg] = fmaxf(hv, 0.f);
        gq[reg] = (hv > 0.f) ? (aT[reg] + pT[reg]) : 0.f;
      }
#pragma unroll
      for (int m = 1; m < 16; m <<= 1) {
#pragma unroll
        for (int reg = 0; reg < 4; ++reg) gq[reg] += __shfl_xor(gq[reg], m);
      }
      if (mrow == 0) {
#pragma unroll
        for (int reg = 0; reg < 4; ++reg) gred[nch * 16 + kg * 4 + reg] = gq[reg];
      }
      int ns = nch * 16 + mrow;            // col within 64-slice
      int kcA = ns >> 5;
      int kgA = ((ns >> 3) & 3);
#pragma unroll
      for (int reg = 0; reg < 4; ++reg) {
        int r = kg * 4 + reg;
        unsigned short uh = bf16_rn(h2v[reg]);
        unsigned short ul = bf16_rn(h2v[reg] - bf16_f(uh));
        int ph = __shfl_xor((int)uh, 1);
        int pl = __shfl_xor((int)ul, 1);
        if ((l & 1) == 0) {
          int base = ((kcA * 64 + kgA * 16 + r) << 3) + (ns & 7);
          *(unsigned int*)(h2h + base) = (unsigned int)uh | (((unsigned int)(unsigned short)ph) << 16);
          *(unsigned int*)(h2l + base) = (unsigned int)ul | (((unsigned int)(unsigned short)pl) << 16);
        }
      }
    }
  }
  __syncthreads();

  // ---- phase 3: yPart = h2_slice @ W3_slice; g combine ----
  if (w < 4) {
    f32x4 aA = {0.f, 0.f, 0.f, 0.f};
    f32x4 aB = {0.f, 0.f, 0.f, 0.f};
#pragma unroll
    for (int kc2 = 0; kc2 < 2; ++kc2) {
      short8 Ah = *(const short8*)(h2h + (kc2 * 64 + l) * 8);
      short8 Al = *(const short8*)(h2l + (kc2 * 64 + l) * 8);
      long b3off = (((long)((cs * 2 + kc2) * 4 + w)) * 64 + l) * 8;
      short8 Bh = *(const short8*)(W3h + b3off);
      short8 Bl = *(const short8*)(W3l + b3off);
      aA = MFMA(Ah, Bh, aA);
      aB = MFMA(Ah, Bl, aB);
      aA = MFMA(Al, Bh, aA);
    }
#pragma unroll
    for (int reg = 0; reg < 4; ++reg) {
      int row = r0 + kg * 4 + reg;
      yPartW[((long)cs * NB + row) * DD + w * 16 + mrow] = aA[reg] + aB[reg];
    }
  } else if (w == 4 && l < 16) {
    float g = gred[l] + gred[16 + l] + gred[32 + l] + gred[48 + l];
    gW[cs * NB + r0 + l] = g;
  }
}

// ---------------- k_fin: apply last scan-step's logdet (t=8) ----------------
__global__ __launch_bounds__(512) void k_fin(const float* __restrict__ yPartR,
    const float* __restrict__ gR, const float* __restrict__ SRead,
    const float* __restrict__ b3, float* __restrict__ logdet,
    float dtp, float dtHp) {
  int row = blockIdx.x * 8 + (threadIdx.x >> 6);
  int l = threadIdx.x & 63;
  float yv = b3[l];
#pragma unroll
  for (int s = 0; s < 8; ++s) yv += yPartR[(s * NB + row) * DD + l];
  float sv = yv;
#pragma unroll
  for (int m = 1; m < 64; m <<= 1) sv += __shfl_xor(sv, m);
  if (l == 0) {
    float g = 0.f;
#pragma unroll
    for (int s = 0; s < 8; ++s) g += gR[s * NB + row];
    logdet[row] -= (sv - SRead[row]) * dtHp + g * dtp;
  }
}

// ---------------- pack outputs ----------------
__global__ __launch_bounds__(256) void k_out(const float* __restrict__ z,
    const float* __restrict__ logdet, float* __restrict__ out) {
  int i = blockIdx.x * 256 + threadIdx.x;          // 260*256 = 66560 exactly
  if (i < NB * DD) out[i] = z[i];
  else out[i] = logdet[i - NB * DD];
}

extern "C" void kernel_launch(void* const* d_in, const int* in_sizes, int n_in,
                              void* d_out, int out_size, void* d_ws, size_t ws_size,
                              hipStream_t stream) {
  const float* x  = (const float*)d_in[0];
  const float* W1 = (const float*)d_in[1];
  const float* b1 = (const float*)d_in[2];
  const float* W2 = (const float*)d_in[3];
  const float* b2 = (const float*)d_in[4];
  const float* W3 = (const float*)d_in[5];
  const float* b3 = (const float*)d_in[6];
  float* out = (float*)d_out;

  // ---- workspace ----
  short* sb  = (short*)d_ws;
  short* W2h = sb;                                 // 512*512 each
  short* W2l = W2h + HD * HD;
  short* Ep  = W2l + HD * HD;
  short* W1h = Ep + HD * HD;                       // 64*512 each
  short* W1l = W1h + DD * HD;
  short* W3h = W1l + DD * HD;                      // 512*64 each
  short* W3l = W3h + HD * DD;
  float* fb  = (float*)(W3l + HD * DD);
  float* yP0 = fb;                                 // [8][1024][64] each
  float* yP1 = yP0 + 8 * NB * DD;
  float* gP0 = yP1 + 8 * NB * DD;                  // [8][1024] each
  float* gP1 = gP0 + 8 * NB;
  float* SB0 = gP1 + 8 * NB;                       // [1024] each
  float* SB1 = SB0 + NB;
  float* zb0 = SB1 + NB;                           // [1024][64] each
  float* zb1 = zb0 + NB * DD;
  float* logdet = zb1 + NB * DD;                   // [1024]

  float* yP[2] = {yP0, yP1};
  float* gP[2] = {gP0, gP1};
  float* SB[2] = {SB0, SB1};
  float* zb[2] = {zb0, zb1};

  k_prep<<<64, 512, 0, stream>>>(W1, W2, W3, W1h, W1l, W2h, W2l, Ep, W3h, W3l,
                                 logdet);

  double td[10];
  for (int i = 0; i < 10; ++i) td[i] = (double)i / 9.0;
  float dts[9];
  for (int t = 0; t < 9; ++t) dts[t] = (float)td[t + 1] - (float)td[t];

  for (int k = 0; k <= 9; ++k) {
    const float* zi = (k == 0) ? x : zb[(k - 1) & 1];
    float dtc  = (k >= 1) ? dts[k - 1] : 0.f;
    float dtpv = (k >= 2) ? dts[k - 2] : 0.f;
    int mode = (k == 0) ? 0 : ((k == 1) ? 1 : 2);
    k_step<<<512, 512, 0, stream>>>(zi, zb[k & 1],
        yP[(k + 1) & 1], gP[(k + 1) & 1], SB[k & 1], SB[(k + 1) & 1], logdet,
        b1, b2, b3, W1h, W1l, W2h, W2l, Ep, W3h, W3l,
        yP[k & 1], gP[k & 1], dtc, dtpv, dtpv * 1e5f, mode);
  }
  // apply scan-step t=8 (launch-9 outputs: yP[1], gP[1]; SB[0] = S_8)
  k_fin<<<128, 512, 0, stream>>>(yP[1], gP[1], SB[0], b3, logdet,
                                 dts[8], dts[8] * 1e5f);

  k_out<<<260, 256, 0, stream>>>(zb[1], logdet, out);
}